// Round 8
// baseline (6162.124 us; speedup 1.0000x reference)
//
#include <hip/hip_runtime.h>
#include <stdint.h>

#define NB 16
#define WIN 168
#define NSTEPS 24
#define PAIRS (4096/NB)          // 256 batch-tiles
#define NT 512

typedef __attribute__((ext_vector_type(8))) short bf16x8;
typedef __attribute__((ext_vector_type(4))) float f32x4;

#if __has_builtin(__builtin_amdgcn_rcpf)
#define RCPF(x) __builtin_amdgcn_rcpf(x)
#else
#define RCPF(x) (1.0f / (x))
#endif
#if __has_builtin(__builtin_amdgcn_exp2f)
#define EXP2F(x) __builtin_amdgcn_exp2f(x)
#else
#define EXP2F(x) __expf((x) * 0.6931471805599453f)
#endif

__device__ __forceinline__ float sigm(float x){
  return RCPF(1.0f + EXP2F(x * -1.4426950408889634f));
}
// sigmoid(a)*tanh(b), one rcp (R7, verified absmax-neutral)
__device__ __forceinline__ float sigtanh(float a, float b){
  float A = EXP2F(a * -1.4426950408889634f);
  float B = EXP2F(fabsf(b) * -2.8853900817779268f);
  float t = (1.0f - B) * RCPF((1.0f + A) * (1.0f + B));
  uint32_t sb = __builtin_bit_cast(uint32_t, b) & 0x80000000u;
  return __builtin_bit_cast(float, __builtin_bit_cast(uint32_t, t) ^ sb);
}

__device__ __forceinline__ uint32_t bf_rn(float f){
  uint32_t u = __builtin_bit_cast(uint32_t, f);
  return (u + 0x7FFFu + ((u >> 16) & 1u)) >> 16;
}
__device__ __forceinline__ float bf_f(uint32_t s){
  return __builtin_bit_cast(float, s << 16);
}
__device__ __forceinline__ void split_t(float f, uint32_t& hi, uint32_t& lo){
  uint32_t u = __builtin_bit_cast(uint32_t, f);
  hi = u >> 16;
  lo = bf_rn(f - bf_f(hi));
}
__device__ __forceinline__ void split_s(float f, short& hi, short& lo){
  uint32_t h = bf_rn(f);
  hi = (short)h;
  lo = (short)bf_rn(f - bf_f(h));
}
__device__ __forceinline__ f32x4 mfma16(bf16x8 a, bf16x8 b, f32x4 c){
  return __builtin_amdgcn_mfma_f32_16x16x32_bf16(a, b, c, 0, 0, 0);
}

__device__ __forceinline__ void lstm_epi(const f32x4 acc[4], float c[4], float hn[4]){
  #pragma unroll
  for (int r = 0; r < 4; r++){
    float cn = __builtin_fmaf(sigm(acc[1][r]), c[r], sigtanh(acc[0][r], acc[2][r]));
    c[r] = cn;
    hn[r] = sigtanh(acc[3][r], cn);
  }
}

// LDS frag block: per (hl,kt): 4 q2-rows of 136 shorts (128 data + 8 pad)
#define FROW 136
#define FBLK 544
#define FB(buf,hl,kt) ((((buf)*2 + (hl))*2 + (kt)) * FBLK)
#define BUF_INTS (2*FBLK)

// ws layout
#define HIST_SHORTS ((size_t)PAIRS * WIN * 2048)
#define HIST_BYTES  (HIST_SHORTS * 2)
#define CFIN_FLOATS ((size_t)PAIRS * 1024)
#define CFIN_BYTES  (CFIN_FLOATS * 4)
#define PROG_BYTES  ((size_t)2 * PAIRS * 4)

// ============================================================================
// DECOUPLED kernel: 512 blocks x 256 thr. Even blocks = LSTM1 producer (A),
// odd blocks = LSTM2+FC consumer (B), same pair p = blockIdx>>1. A and B have
// INDEPENDENT per-step barriers; cross-block sync is sweep-granular (Aprog)
// plus a 16-step-granular anti-dependency throttle (Bprog) so A never
// overwrites a hist slot B hasn't retired. All co-resident by capacity:
// LDS 50KB -> 3 blk/CU, launch_bounds(256,2) -> >=2 blk/CU. 512 <= 2*256.
// ============================================================================
__global__ __launch_bounds__(256, 2) void lstm_decoupled_kernel(
  const float* __restrict__ x,    const float* __restrict__ Wih1, const float* __restrict__ Whh1,
  const float* __restrict__ bih1, const float* __restrict__ bhh1,
  const float* __restrict__ Wih2, const float* __restrict__ Whh2,
  const float* __restrict__ bih2, const float* __restrict__ bhh2,
  const float* __restrict__ fc1w, const float* __restrict__ fc1b,
  const float* __restrict__ fc2w, const float* __restrict__ fc2b,
  float* __restrict__ out, short* __restrict__ hist,
  float* __restrict__ cfin, unsigned* __restrict__ prog)
{
  __shared__ __align__(16) short aS[2*2*2*FBLK];   // A: LSTM1 state dbuf
  __shared__ __align__(16) short bS[2*2*2*FBLK];   // B: LSTM2 state dbuf
  __shared__ float win_s[WIN][NB];                 // A
  __shared__ float Hlast[NB][68];                  // B
  __shared__ float fc1w_s[64*68];                  // B
  __shared__ float dval_s[NB];                     // B

  const int p   = blockIdx.x >> 1;
  const bool isA = (blockIdx.x & 1) == 0;
  const int tid = threadIdx.x;
  const int wv  = tid >> 6;          // 0..3
  const int ln  = tid & 63;
  const int q   = ln >> 4;
  const int n   = ln & 15;
  const int bg0 = p * NB;
  const int u0  = 16*wv + 4*q;
  const int kt_  = u0 >> 5;
  const int q2_  = (u0 >> 3) & 3;
  const int jj0_ = u0 & 7;
  const int rdo  = q*FROW + n*8;
  const int wro  = q2_*FROW + n*8 + jj0_;
  const int gwo  = kt_*512 + q2_*128 + n*8 + jj0_;
  const int ro   = q*128 + n*8;
  short*    __restrict__ hblk = hist + (size_t)p * WIN * 2048;
  float*    __restrict__ cfp  = cfin + (size_t)p * 1024;     // [u*16+n]
  unsigned* Ap = prog + p;
  unsigned* Bp = prog + PAIRS + p;

  if (isA){
    // =================== A-block: LSTM1 producer ===================
    for (int i = tid; i < WIN*NB; i += 256){ int t = i >> 4, b = i & 15; win_s[t][b] = x[(bg0 + b)*169 + t]; }

    bf16x8 A1hi[4][2], A1lo[4][2], Ain1[4];
    f32x4 b1c[4];
    #pragma unroll
    for (int e = 0; e < 4; e++){
      const int ja = 64*e + 16*wv + n;
      #pragma unroll
      for (int kt = 0; kt < 2; kt++){
        const float* pw = Whh1 + ja*64 + kt*32 + q*8;
        #pragma unroll
        for (int jj = 0; jj < 8; jj++){ short h,l; split_s(pw[jj], h, l); A1hi[e][kt][jj] = h; A1lo[e][kt][jj] = l; }
      }
      bf16x8 ain = {0,0,0,0,0,0,0,0};
      if (q == 0){ short wh, wl; split_s(Wih1[ja], wh, wl); ain[0] = wh; ain[1] = wh; ain[2] = wl; }
      Ain1[e] = ain;
      const int jc = 64*e + u0;
      #pragma unroll
      for (int r = 0; r < 4; r++) b1c[e][r] = bih1[jc+r] + bhh1[jc+r];
    }
    float c1[4];
    unsigned bp_cache = 0;

    for (int sg = 0; sg < NSTEPS; sg++){
      #pragma unroll
      for (int r = 0; r < 4; r++) c1[r] = 0.0f;
      int slot = sg;
      for (int t = 0; t < WIN; t++){
        const int g = sg*WIN + t;
        // anti-dependency throttle: B must have retired old slot t
        if (tid == 0){
          const int limit = g - (WIN - 1);
          if ((int)bp_cache < limit){
            while ((int)(bp_cache = atomicAdd(Bp, 0u)) < limit) __builtin_amdgcn_s_sleep(8);
          }
        }
        __syncthreads();
        if (t == WIN-1 && sg > 0){
          // out(sg-1) ready (throttle implies Bprog >= sg*WIN => B's FC done)
          if (tid == 0) __threadfence();   // acquire: invalidate for fresh out
          __syncthreads();
          if (tid < NB) win_s[sg-1][tid] = out[(bg0 + tid)*24 + (sg-1)];
          __syncthreads();
        }
        // ---- LSTM1 step
        {
          const int rb = t & 1, wb = rb ^ 1;
          const bool first = (t == 0);
          f32x4 acc[4];
          bf16x8 bin = {0,0,0,0,0,0,0,0};
          { float xv = win_s[slot][n]; uint32_t xh, xl; split_t(xv, xh, xl);
            if (q == 0){ bin[0] = (short)xh; bin[1] = (short)xl; bin[2] = (short)xh; } }
          if (first){
            #pragma unroll
            for (int e = 0; e < 4; e++) acc[e] = mfma16(Ain1[e], bin, b1c[e]);
          } else {
            bf16x8 Bh0 = *(const bf16x8*)&aS[FB(rb,0,0)+rdo];
            bf16x8 Bl0 = *(const bf16x8*)&aS[FB(rb,1,0)+rdo];
            bf16x8 Bh1 = *(const bf16x8*)&aS[FB(rb,0,1)+rdo];
            bf16x8 Bl1 = *(const bf16x8*)&aS[FB(rb,1,1)+rdo];
            #pragma unroll
            for (int e = 0; e < 4; e++){
              f32x4 a = b1c[e];
              a = mfma16(A1hi[e][0], Bh0, a);
              a = mfma16(A1hi[e][0], Bl0, a);
              a = mfma16(A1lo[e][0], Bh0, a);
              a = mfma16(A1hi[e][1], Bh1, a);
              a = mfma16(A1hi[e][1], Bl1, a);
              a = mfma16(A1lo[e][1], Bh1, a);
              a = mfma16(Ain1[e], bin, a);
              acc[e] = a;
            }
          }
          float hn[4];
          lstm_epi(acc, c1, hn);
          uint32_t ph[4], pl[4];
          #pragma unroll
          for (int r = 0; r < 4; r++) split_t(hn[r], ph[r], pl[r]);
          *(uint2*)&aS[FB(wb,0,kt_)+wro] = make_uint2(ph[0] | (ph[1]<<16), ph[2] | (ph[3]<<16));
          *(uint2*)&aS[FB(wb,1,kt_)+wro] = make_uint2(pl[0] | (pl[1]<<16), pl[2] | (pl[3]<<16));
          short* Hp = hblk + (size_t)t * 2048;
          if (t < WIN-1){
            // relu'd h for B's L1 input
            uint32_t sh[4], sl[4];
            #pragma unroll
            for (int r = 0; r < 4; r++){ bool pos = hn[r] > 0.0f; sh[r] = pos ? ph[r] : 0u; sl[r] = pos ? pl[r] : 0u; }
            *(uint2*)&Hp[gwo]        = make_uint2(sh[0] | (sh[1]<<16), sh[2] | (sh[3]<<16));
            *(uint2*)&Hp[1024 + gwo] = make_uint2(sl[0] | (sl[1]<<16), sl[2] | (sl[3]<<16));
          } else {
            // slot 167 RAW: doubles as B's h2-init; B applies relu in-register
            *(uint2*)&Hp[gwo]        = make_uint2(ph[0] | (ph[1]<<16), ph[2] | (ph[3]<<16));
            *(uint2*)&Hp[1024 + gwo] = make_uint2(pl[0] | (pl[1]<<16), pl[2] | (pl[3]<<16));
          }
        }
        slot++; if (slot == WIN) slot = 0;
      }
      // finals + release
      #pragma unroll
      for (int r = 0; r < 4; r++) cfp[(u0 + r)*16 + n] = c1[r];
      __syncthreads();   // per-wave vmcnt(0): all hist/cfin stores retired
      if (tid == 0){ __threadfence(); atomicExch(Ap, (unsigned)((sg+1)*WIN)); }
    }

  } else {
    // =================== B-block: LSTM2 + FC consumer ===================
    for (int i = tid; i < 64*65; i += 256){ int j = i / 65, k = i % 65; fc1w_s[j*68 + k] = fc1w[i]; }
    if (tid < NB) dval_s[tid] = x[(bg0 + tid)*169 + 168];

    bf16x8 A2hi[4][4], A2lo[4][4];
    f32x4 b2c[4];
    #pragma unroll
    for (int e = 0; e < 4; e++){
      const int ja = 64*e + 16*wv + n;
      #pragma unroll
      for (int kt = 0; kt < 4; kt++){
        const float* pw = (kt < 2 ? (Wih2 + ja*64 + kt*32) : (Whh2 + ja*64 + (kt-2)*32)) + q*8;
        #pragma unroll
        for (int jj = 0; jj < 8; jj++){ short h,l; split_s(pw[jj], h, l); A2hi[e][kt][jj] = h; A2lo[e][kt][jj] = l; }
      }
      const int jc = 64*e + u0;
      #pragma unroll
      for (int r = 0; r < 4; r++) b2c[e][r] = bih2[jc+r] + bhh2[jc+r];
    }
    const float fc1b_r = fc1b[ln];
    const float fc2w_r = fc2w[ln];
    const float fc2b_r = fc2b[0];
    float c2[4];
    bf16x8 ch0, cl0, ch1, cl1, nh0, nl0, nh1, nl1;

    auto loadn = [&](int t){
      const short* Hp = hblk + (size_t)t * 2048;
      nh0 = *(const bf16x8*)&Hp[ro];
      nl0 = *(const bf16x8*)&Hp[1024 + ro];
      nh1 = *(const bf16x8*)&Hp[512 + ro];
      nl1 = *(const bf16x8*)&Hp[1536 + ro];
    };
    auto relufix = [&](bf16x8& h, bf16x8& l){
      #pragma unroll
      for (int j = 0; j < 8; j++){
        bool neg = (h[j] & (short)0x8000) != 0;
        h[j] = neg ? (short)0 : h[j];
        l[j] = neg ? (short)0 : l[j];
      }
    };

    for (int sb = 0; sb < NSTEPS; sb++){
      // wait for A to finish sweep sb (hist + cfin released)
      if (tid == 0){
        const unsigned need_a = (unsigned)((sb+1)*WIN);
        while (atomicAdd(Ap, 0u) < need_a) __builtin_amdgcn_s_sleep(8);
        __threadfence();                 // acquire: fresh hist/cfin
      }
      __syncthreads();
      #pragma unroll
      for (int r = 0; r < 4; r++) c2[r] = cfp[(u0 + r)*16 + n];
      // seed bS[0] with h2-init = raw h1-final (hist slot 167)
      {
        const short* Hp = hblk + (size_t)(WIN-1) * 2048;
        bf16x8 s0 = *(const bf16x8*)&Hp[ro];
        bf16x8 s1 = *(const bf16x8*)&Hp[1024 + ro];
        bf16x8 s2 = *(const bf16x8*)&Hp[512 + ro];
        bf16x8 s3 = *(const bf16x8*)&Hp[1536 + ro];
        if (wv == 0){
          *(bf16x8*)&bS[FB(0,0,0)+rdo] = s0;
          *(bf16x8*)&bS[FB(0,1,0)+rdo] = s1;
          *(bf16x8*)&bS[FB(0,0,1)+rdo] = s2;
          *(bf16x8*)&bS[FB(0,1,1)+rdo] = s3;
        }
      }
      loadn(0); ch0 = nh0; cl0 = nl0; ch1 = nh1; cl1 = nl1;   // slot 0 current
      __syncthreads();                   // seed visible to all waves

      for (int t = 0; t < WIN; t++){
        if (t < WIN-1) loadn(t + 1);
        if (t){
          __syncthreads();               // per-wave vmcnt(0): slots <= t retired
          if (tid == 0 && (t & 15) == 0) atomicExch(Bp, (unsigned)(sb*WIN + t));
        }
        const bool last = (t == WIN-1);
        if (last){ relufix(ch0, cl0); relufix(ch1, cl1); }   // slot167 is raw
        {
          const int rb = t & 1, wb = rb ^ 1;
          bf16x8 L2h0 = *(const bf16x8*)&bS[FB(rb,0,0)+rdo];
          bf16x8 L2l0 = *(const bf16x8*)&bS[FB(rb,1,0)+rdo];
          bf16x8 L2h1 = *(const bf16x8*)&bS[FB(rb,0,1)+rdo];
          bf16x8 L2l1 = *(const bf16x8*)&bS[FB(rb,1,1)+rdo];
          f32x4 acc[4];
          #pragma unroll
          for (int e = 0; e < 4; e++){
            f32x4 a = b2c[e];
            a = mfma16(A2hi[e][0], ch0, a);
            a = mfma16(A2hi[e][0], cl0, a);
            a = mfma16(A2lo[e][0], ch0, a);
            a = mfma16(A2hi[e][1], ch1, a);
            a = mfma16(A2hi[e][1], cl1, a);
            a = mfma16(A2lo[e][1], ch1, a);
            a = mfma16(A2hi[e][2], L2h0, a);
            a = mfma16(A2hi[e][2], L2l0, a);
            a = mfma16(A2lo[e][2], L2h0, a);
            a = mfma16(A2hi[e][3], L2h1, a);
            a = mfma16(A2hi[e][3], L2l1, a);
            a = mfma16(A2lo[e][3], L2h1, a);
            acc[e] = a;
          }
          float hn[4];
          lstm_epi(acc, c2, hn);
          if (!last){
            uint32_t ph[4], pl[4];
            #pragma unroll
            for (int r = 0; r < 4; r++) split_t(hn[r], ph[r], pl[r]);
            *(uint2*)&bS[FB(wb,0,kt_)+wro] = make_uint2(ph[0] | (ph[1]<<16), ph[2] | (ph[3]<<16));
            *(uint2*)&bS[FB(wb,1,kt_)+wro] = make_uint2(pl[0] | (pl[1]<<16), pl[2] | (pl[3]<<16));
          } else {
            #pragma unroll
            for (int r = 0; r < 4; r++) Hlast[n][u0 + r] = fmaxf(hn[r], 0.0f);
          }
        }
        ch0 = nh0; cl0 = nl0; ch1 = nh1; cl1 = nl1;
      }
      __syncthreads();
      // FC head: 4 waves x 4 batches
      {
        float o4[4];
        #pragma unroll
        for (int bi = 0; bi < 4; bi++){
          const int b = 4*wv + bi;
          float a1 = fc1b_r;
          #pragma unroll
          for (int k4 = 0; k4 < 16; k4++){
            const float* wp = &fc1w_s[ln*68 + k4*4];
            const float* hp = &Hlast[b][k4*4];
            a1 += wp[0]*hp[0] + wp[1]*hp[1] + wp[2]*hp[2] + wp[3]*hp[3];
          }
          a1 += dval_s[b] * fc1w_s[ln*68 + 64];
          float v = a1 * fc2w_r;
          #pragma unroll
          for (int off = 32; off > 0; off >>= 1) v += __shfl_xor(v, off);
          o4[bi] = v + fc2b_r;
        }
        if (ln == 0){
          #pragma unroll
          for (int bi = 0; bi < 4; bi++) out[(bg0 + 4*wv + bi)*24 + sb] = o4[bi];
        }
      }
      __syncthreads();                   // out stores retired (per-wave vmcnt)
      if (tid == 0){ __threadfence(); atomicExch(Bp, (unsigned)((sb+1)*WIN)); }
    }
  }
}

// ============================================================================
// Middle tier (ws fits hist only): R7 fused wave-specialized kernel.
// ============================================================================
__global__ __launch_bounds__(NT, 2) void lstm_fused_kernel(
  const float* __restrict__ x,    const float* __restrict__ Wih1, const float* __restrict__ Whh1,
  const float* __restrict__ bih1, const float* __restrict__ bhh1,
  const float* __restrict__ Wih2, const float* __restrict__ Whh2,
  const float* __restrict__ bih2, const float* __restrict__ bhh2,
  const float* __restrict__ fc1w, const float* __restrict__ fc1b,
  const float* __restrict__ fc2w, const float* __restrict__ fc2b,
  float* __restrict__ out, short* __restrict__ hist)
{
  __shared__ __align__(16) short aS[2*2*2*FBLK];
  __shared__ __align__(16) short bS[2*2*2*FBLK];
  __shared__ float cS[64][16];
  __shared__ float win_s[WIN][NB];
  __shared__ float Hlast[NB][68];
  __shared__ float fc1w_s[64*68];
  __shared__ float dval_s[NB];

  const int tid = threadIdx.x;
  const int wv8 = tid >> 6;
  const int wv  = wv8 & 3;
  const bool isA = (wv8 < 4);
  const int ln  = tid & 63;
  const int q   = ln >> 4;
  const int n   = ln & 15;
  const int bg0 = blockIdx.x * NB;
  const int u0  = 16*wv + 4*q;
  const int kt_  = u0 >> 5;
  const int q2_  = (u0 >> 3) & 3;
  const int jj0_ = u0 & 7;
  const int rdo  = q*FROW + n*8;
  const int wro  = q2_*FROW + n*8 + jj0_;
  const int gwo  = kt_*512 + q2_*128 + n*8 + jj0_;
  const int ro   = q*128 + n*8;
  short* __restrict__ hblk = hist + (size_t)blockIdx.x * WIN * 2048;

  for (int i = tid; i < WIN*NB; i += NT){ int t = i >> 4, b = i & 15; win_s[t][b] = x[(bg0 + b)*169 + t]; }
  for (int i = tid; i < 64*65; i += NT){ int j = i / 65, k = i % 65; fc1w_s[j*68 + k] = fc1w[i]; }
  if (tid < NB) dval_s[tid] = x[(bg0 + tid)*169 + 168];

  const float fc1b_r = fc1b[ln];
  const float fc2w_r = fc2w[ln];
  const float fc2b_r = fc2b[0];

  auto fc_head = [&](int s){
    float o2[2];
    #pragma unroll
    for (int bi = 0; bi < 2; bi++){
      const int b = 2*wv8 + bi;
      float a1 = fc1b_r;
      #pragma unroll
      for (int k4 = 0; k4 < 16; k4++){
        const float* wp = &fc1w_s[ln*68 + k4*4];
        const float* hp = &Hlast[b][k4*4];
        a1 += wp[0]*hp[0] + wp[1]*hp[1] + wp[2]*hp[2] + wp[3]*hp[3];
      }
      a1 += dval_s[b] * fc1w_s[ln*68 + 64];
      float v = a1 * fc2w_r;
      #pragma unroll
      for (int off = 32; off > 0; off >>= 1) v += __shfl_xor(v, off);
      o2[bi] = v + fc2b_r;
    }
    if (ln == 0){
      #pragma unroll
      for (int bi = 0; bi < 2; bi++){
        const int b = 2*wv8 + bi;
        out[(bg0 + b)*24 + s] = o2[bi];
        win_s[s % WIN][b] = o2[bi];
      }
    }
  };

  if (isA){
    bf16x8 A1hi[4][2], A1lo[4][2], Ain1[4];
    f32x4 b1c[4];
    #pragma unroll
    for (int e = 0; e < 4; e++){
      const int ja = 64*e + 16*wv + n;
      #pragma unroll
      for (int kt = 0; kt < 2; kt++){
        const float* pw = Whh1 + ja*64 + kt*32 + q*8;
        #pragma unroll
        for (int jj = 0; jj < 8; jj++){ short h,l; split_s(pw[jj], h, l); A1hi[e][kt][jj] = h; A1lo[e][kt][jj] = l; }
      }
      bf16x8 ain = {0,0,0,0,0,0,0,0};
      if (q == 0){ short wh, wl; split_s(Wih1[ja], wh, wl); ain[0] = wh; ain[1] = wh; ain[2] = wl; }
      Ain1[e] = ain;
      const int jc = 64*e + u0;
      #pragma unroll
      for (int r = 0; r < 4; r++) b1c[e][r] = bih1[jc+r] + bhh1[jc+r];
    }
    float c1[4];

    auto lstm1 = [&](int rb, int wb, int slot, int t, bool first){
      f32x4 acc[4];
      bf16x8 bin = {0,0,0,0,0,0,0,0};
      { float xv = win_s[slot][n]; uint32_t xh, xl; split_t(xv, xh, xl);
        if (q == 0){ bin[0] = (short)xh; bin[1] = (short)xl; bin[2] = (short)xh; } }
      if (first){
        #pragma unroll
        for (int e = 0; e < 4; e++) acc[e] = mfma16(Ain1[e], bin, b1c[e]);
      } else {
        bf16x8 Bh0 = *(const bf16x8*)&aS[FB(rb,0,0)+rdo];
        bf16x8 Bl0 = *(const bf16x8*)&aS[FB(rb,1,0)+rdo];
        bf16x8 Bh1 = *(const bf16x8*)&aS[FB(rb,0,1)+rdo];
        bf16x8 Bl1 = *(const bf16x8*)&aS[FB(rb,1,1)+rdo];
        #pragma unroll
        for (int e = 0; e < 4; e++){
          f32x4 a = b1c[e];
          a = mfma16(A1hi[e][0], Bh0, a);
          a = mfma16(A1hi[e][0], Bl0, a);
          a = mfma16(A1lo[e][0], Bh0, a);
          a = mfma16(A1hi[e][1], Bh1, a);
          a = mfma16(A1hi[e][1], Bl1, a);
          a = mfma16(A1lo[e][1], Bh1, a);
          a = mfma16(Ain1[e], bin, a);
          acc[e] = a;
        }
      }
      float hn[4];
      lstm_epi(acc, c1, hn);
      uint32_t ph[4], pl[4];
      #pragma unroll
      for (int r = 0; r < 4; r++) split_t(hn[r], ph[r], pl[r]);
      *(uint2*)&aS[FB(wb,0,kt_)+wro] = make_uint2(ph[0] | (ph[1]<<16), ph[2] | (ph[3]<<16));
      *(uint2*)&aS[FB(wb,1,kt_)+wro] = make_uint2(pl[0] | (pl[1]<<16), pl[2] | (pl[3]<<16));
      uint32_t sh[4], sl[4];
      #pragma unroll
      for (int r = 0; r < 4; r++){ bool pos = hn[r] > 0.0f; sh[r] = pos ? ph[r] : 0u; sl[r] = pos ? pl[r] : 0u; }
      short* Hp = hblk + (size_t)t * 2048;
      *(uint2*)&Hp[gwo]        = make_uint2(sh[0] | (sh[1]<<16), sh[2] | (sh[3]<<16));
      *(uint2*)&Hp[1024 + gwo] = make_uint2(sl[0] | (sl[1]<<16), sl[2] | (sl[3]<<16));
    };

    #pragma unroll
    for (int r = 0; r < 4; r++) c1[r] = 0.0f;
    for (int t = 0; t < WIN; t++){
      __syncthreads();
      lstm1(t & 1, (t & 1) ^ 1, t, t, t == 0);
    }
    #pragma unroll
    for (int r = 0; r < 4; r++) cS[u0 + r][n] = c1[r];

    for (int sg = 1; sg < NSTEPS; sg++){
      #pragma unroll
      for (int r = 0; r < 4; r++) c1[r] = 0.0f;
      int slot = sg;
      __syncthreads();
      lstm1(0, 1, slot, 0, true);
      slot++;
      for (int t = 1; t < WIN-1; t++){
        __syncthreads();
        lstm1(t & 1, (t & 1) ^ 1, slot, t, false);
        slot++; if (slot == WIN) slot = 0;
      }
      __syncthreads();
      __syncthreads();
      fc_head(sg - 1);
      __syncthreads();
      lstm1(1, 0, slot, WIN-1, false);
      #pragma unroll
      for (int r = 0; r < 4; r++) cS[u0 + r][n] = c1[r];
    }
    for (int i = 0; i < WIN + 1; i++) __syncthreads();
    fc_head(NSTEPS - 1);

  } else {
    bf16x8 A2hi[4][4], A2lo[4][4];
    f32x4 b2c[4];
    #pragma unroll
    for (int e = 0; e < 4; e++){
      const int ja = 64*e + 16*wv + n;
      #pragma unroll
      for (int kt = 0; kt < 4; kt++){
        const float* pw = (kt < 2 ? (Wih2 + ja*64 + kt*32) : (Whh2 + ja*64 + (kt-2)*32)) + q*8;
        #pragma unroll
        for (int jj = 0; jj < 8; jj++){ short h,l; split_s(pw[jj], h, l); A2hi[e][kt][jj] = h; A2lo[e][kt][jj] = l; }
      }
      const int jc = 64*e + u0;
      #pragma unroll
      for (int r = 0; r < 4; r++) b2c[e][r] = bih2[jc+r] + bhh2[jc+r];
    }
    float c2[4];
    bf16x8 ch0, cl0, ch1, cl1, nh0, nl0, nh1, nl1;

    auto loadc = [&](int t){
      const short* Hp = hblk + (size_t)t * 2048;
      ch0 = *(const bf16x8*)&Hp[ro];
      cl0 = *(const bf16x8*)&Hp[1024 + ro];
      ch1 = *(const bf16x8*)&Hp[512 + ro];
      cl1 = *(const bf16x8*)&Hp[1536 + ro];
    };
    auto loadn = [&](int t){
      const short* Hp = hblk + (size_t)t * 2048;
      nh0 = *(const bf16x8*)&Hp[ro];
      nl0 = *(const bf16x8*)&Hp[1024 + ro];
      nh1 = *(const bf16x8*)&Hp[512 + ro];
      nl1 = *(const bf16x8*)&Hp[1536 + ro];
    };
    auto shift = [&](){ ch0 = nh0; cl0 = nl0; ch1 = nh1; cl1 = nl1; };

    auto lstm2 = [&](const short* Sr, int rb, short* Sw, int wb, bool last){
      bf16x8 L2h0 = *(const bf16x8*)&Sr[FB(rb,0,0)+rdo];
      bf16x8 L2l0 = *(const bf16x8*)&Sr[FB(rb,1,0)+rdo];
      bf16x8 L2h1 = *(const bf16x8*)&Sr[FB(rb,0,1)+rdo];
      bf16x8 L2l1 = *(const bf16x8*)&Sr[FB(rb,1,1)+rdo];
      f32x4 acc[4];
      #pragma unroll
      for (int e = 0; e < 4; e++){
        f32x4 a = b2c[e];
        a = mfma16(A2hi[e][0], ch0, a);
        a = mfma16(A2hi[e][0], cl0, a);
        a = mfma16(A2lo[e][0], ch0, a);
        a = mfma16(A2hi[e][1], ch1, a);
        a = mfma16(A2hi[e][1], cl1, a);
        a = mfma16(A2lo[e][1], ch1, a);
        a = mfma16(A2hi[e][2], L2h0, a);
        a = mfma16(A2hi[e][2], L2l0, a);
        a = mfma16(A2lo[e][2], L2h0, a);
        a = mfma16(A2hi[e][3], L2h1, a);
        a = mfma16(A2hi[e][3], L2l1, a);
        a = mfma16(A2lo[e][3], L2h1, a);
        acc[e] = a;
      }
      float hn[4];
      lstm_epi(acc, c2, hn);
      if (!last){
        uint32_t ph[4], pl[4];
        #pragma unroll
        for (int r = 0; r < 4; r++) split_t(hn[r], ph[r], pl[r]);
        *(uint2*)&Sw[FB(wb,0,kt_)+wro] = make_uint2(ph[0] | (ph[1]<<16), ph[2] | (ph[3]<<16));
        *(uint2*)&Sw[FB(wb,1,kt_)+wro] = make_uint2(pl[0] | (pl[1]<<16), pl[2] | (pl[3]<<16));
      } else {
        #pragma unroll
        for (int r = 0; r < 4; r++) Hlast[n][u0 + r] = fmaxf(hn[r], 0.0f);
      }
    };

    for (int i = 0; i < WIN; i++) __syncthreads();

    for (int sg = 1; sg < NSTEPS; sg++){
      loadc(0);
      loadn(1);
      __syncthreads();
      #pragma unroll
      for (int r = 0; r < 4; r++) c2[r] = cS[u0 + r][n];
      lstm2(aS, 0, bS, 1, false);
      shift();
      for (int t = 1; t < WIN-1; t++){
        loadn(t + 1);
        __syncthreads();
        lstm2(bS, t & 1, bS, (t & 1) ^ 1, false);
        shift();
      }
      __syncthreads();
      lstm2(bS, 1, bS, 0, true);
      __syncthreads();
      fc_head(sg - 1);
      __syncthreads();
    }
    {
      loadc(0);
      loadn(1);
      __syncthreads();
      #pragma unroll
      for (int r = 0; r < 4; r++) c2[r] = cS[u0 + r][n];
      lstm2(aS, 0, bS, 1, false);
      shift();
      for (int t = 1; t < WIN; t++){
        if (t < WIN-1) loadn(t + 1);
        __syncthreads();
        lstm2(bS, t & 1, bS, (t & 1) ^ 1, t == WIN-1);
        shift();
      }
      __syncthreads();
      fc_head(NSTEPS - 1);
    }
  }
}

extern "C" void kernel_launch(void* const* d_in, const int* in_sizes, int n_in,
                              void* d_out, int out_size, void* d_ws, size_t ws_size,
                              hipStream_t stream) {
  (void)in_sizes; (void)n_in; (void)out_size;
  const size_t need_old = HIST_BYTES;                             // ~176 MB
  const size_t need_new = HIST_BYTES + CFIN_BYTES + PROG_BYTES;   // ~177.2 MB
  if (ws_size >= need_new){
    char* ws = (char*)d_ws;
    short*    hist = (short*)ws;
    float*    cfin = (float*)(ws + HIST_BYTES);
    unsigned* prog = (unsigned*)(ws + HIST_BYTES + CFIN_BYTES);
    hipMemsetAsync((void*)prog, 0, PROG_BYTES, stream);
    lstm_decoupled_kernel<<<dim3(2*PAIRS), dim3(256), 0, stream>>>(
        (const float*)d_in[0], (const float*)d_in[1], (const float*)d_in[2],
        (const float*)d_in[3], (const float*)d_in[4], (const float*)d_in[5],
        (const float*)d_in[6], (const float*)d_in[7], (const float*)d_in[8],
        (const float*)d_in[9], (const float*)d_in[10], (const float*)d_in[11],
        (const float*)d_in[12], (float*)d_out, hist, cfin, prog);
  } else if (ws_size >= need_old){
    lstm_fused_kernel<<<dim3(PAIRS), dim3(NT), 0, stream>>>(
        (const float*)d_in[0], (const float*)d_in[1], (const float*)d_in[2],
        (const float*)d_in[3], (const float*)d_in[4], (const float*)d_in[5],
        (const float*)d_in[6], (const float*)d_in[7], (const float*)d_in[8],
        (const float*)d_in[9], (const float*)d_in[10], (const float*)d_in[11],
        (const float*)d_in[12], (float*)d_out, (short*)d_ws);
  }
  // (no third tier: ws has been >= need_old in all prior rounds)
}

// Round 9
// 4958.445 us; speedup vs baseline: 1.2428x; 1.2428x over previous
//
#include <hip/hip_runtime.h>
#include <stdint.h>

#define NB 16
#define WIN 168
#define NSTEPS 24
#define NBLK (4096/NB)
#define NT 512

typedef __attribute__((ext_vector_type(8))) short bf16x8;
typedef __attribute__((ext_vector_type(4))) float f32x4;

#if __has_builtin(__builtin_amdgcn_rcpf)
#define RCPF(x) __builtin_amdgcn_rcpf(x)
#else
#define RCPF(x) (1.0f / (x))
#endif
#if __has_builtin(__builtin_amdgcn_exp2f)
#define EXP2F(x) __builtin_amdgcn_exp2f(x)
#else
#define EXP2F(x) __expf((x) * 0.6931471805599453f)
#endif

__device__ __forceinline__ float sigm(float x){
  return RCPF(1.0f + EXP2F(x * -1.4426950408889634f));
}
// sigmoid(a)*tanh(b), one rcp (R7, verified absmax-neutral)
__device__ __forceinline__ float sigtanh(float a, float b){
  float A = EXP2F(a * -1.4426950408889634f);
  float B = EXP2F(fabsf(b) * -2.8853900817779268f);
  float t = (1.0f - B) * RCPF((1.0f + A) * (1.0f + B));
  uint32_t sb = __builtin_bit_cast(uint32_t, b) & 0x80000000u;
  return __builtin_bit_cast(float, __builtin_bit_cast(uint32_t, t) ^ sb);
}

__device__ __forceinline__ uint32_t bf_rn(float f){
  uint32_t u = __builtin_bit_cast(uint32_t, f);
  return (u + 0x7FFFu + ((u >> 16) & 1u)) >> 16;
}
__device__ __forceinline__ float bf_f(uint32_t s){
  return __builtin_bit_cast(float, s << 16);
}
__device__ __forceinline__ void split_t(float f, uint32_t& hi, uint32_t& lo){
  uint32_t u = __builtin_bit_cast(uint32_t, f);
  hi = u >> 16;
  lo = bf_rn(f - bf_f(hi));
}
__device__ __forceinline__ void split_s(float f, short& hi, short& lo){
  uint32_t h = bf_rn(f);
  hi = (short)h;
  lo = (short)bf_rn(f - bf_f(h));
}
__device__ __forceinline__ f32x4 mfma16(bf16x8 a, bf16x8 b, f32x4 c){
  return __builtin_amdgcn_mfma_f32_16x16x32_bf16(a, b, c, 0, 0, 0);
}

__device__ __forceinline__ void lstm_epi(const f32x4 acc[4], float c[4], float hn[4]){
  #pragma unroll
  for (int r = 0; r < 4; r++){
    float cn = __builtin_fmaf(sigm(acc[1][r]), c[r], sigtanh(acc[0][r], acc[2][r]));
    c[r] = cn;
    hn[r] = sigtanh(acc[3][r], cn);
  }
}

// LDS frag block: per (hl,kt): 4 q2-rows of 136 shorts (128 data + 8 pad)
#define FROW 136
#define FBLK 544
#define FB(buf,hl,kt) ((((buf)*2 + (hl))*2 + (kt)) * FBLK)
#define BUF_INTS (2*FBLK)

// ============================================================================
// FUSED + WAVE-SPECIALIZED kernel (R7 base). R9 change: B's hist prefetch
// loadn(t+1) is issued AFTER the interval's __syncthreads, not before. R7
// issued it right before the barrier, whose implicit s_waitcnt vmcnt(0)
// exposed the full L3/HBM latency (~300-900 cyc) EVERY interval. Hoisted, the
// load has the whole interval to complete and drains free at the next
// barrier. Race-free: A writes hist slot t+1 during interval t+1, strictly
// after the barrier that completes B's load of slot t+1. Sweep-seed loads
// (loadc(0)/loadn(1)) must stay pre-barrier (A overwrites slot 0 in interval
// 0) -- once-per-sweep drain, negligible.
// ============================================================================
__global__ __launch_bounds__(NT, 2) void lstm_fused_kernel(
  const float* __restrict__ x,    const float* __restrict__ Wih1, const float* __restrict__ Whh1,
  const float* __restrict__ bih1, const float* __restrict__ bhh1,
  const float* __restrict__ Wih2, const float* __restrict__ Whh2,
  const float* __restrict__ bih2, const float* __restrict__ bhh2,
  const float* __restrict__ fc1w, const float* __restrict__ fc1b,
  const float* __restrict__ fc2w, const float* __restrict__ fc2b,
  float* __restrict__ out, short* __restrict__ hist)
{
  __shared__ __align__(16) short aS[2*2*2*FBLK];   // LSTM1 state dbuf
  __shared__ __align__(16) short bS[2*2*2*FBLK];   // LSTM2 state dbuf
  __shared__ float cS[64][16];                     // c1-final handoff A->B
  __shared__ float win_s[WIN][NB];
  __shared__ float Hlast[NB][68];
  __shared__ float fc1w_s[64*68];
  __shared__ float dval_s[NB];

  const int tid = threadIdx.x;
  const int wv8 = tid >> 6;          // 0..7
  const int wv  = wv8 & 3;           // role-local wave id 0..3
  const bool isA = (wv8 < 4);
  const int ln  = tid & 63;
  const int q   = ln >> 4;
  const int n   = ln & 15;
  const int bg0 = blockIdx.x * NB;
  const int u0  = 16*wv + 4*q;
  const int kt_  = u0 >> 5;
  const int q2_  = (u0 >> 3) & 3;
  const int jj0_ = u0 & 7;                          // {0,4}
  const int rdo  = q*FROW + n*8;                    // frag read offset
  const int wro  = q2_*FROW + n*8 + jj0_;           // frag write offset
  const int gwo  = kt_*512 + q2_*128 + n*8 + jj0_;  // hist write offset
  const int ro   = q*128 + n*8;                     // hist read offset
  short* __restrict__ hblk = hist + (size_t)blockIdx.x * WIN * 2048;

  for (int i = tid; i < WIN*NB; i += NT){ int t = i >> 4, b = i & 15; win_s[t][b] = x[(bg0 + b)*169 + t]; }
  for (int i = tid; i < 64*65; i += NT){ int j = i / 65, k = i % 65; fc1w_s[j*68 + k] = fc1w[i]; }
  if (tid < NB) dval_s[tid] = x[(bg0 + tid)*169 + 168];

  const float fc1b_r = fc1b[ln];
  const float fc2w_r = fc2w[ln];
  const float fc2b_r = fc2b[0];

  // FC head: all 8 waves, 2 batches each.
  auto fc_head = [&](int s){
    float o2[2];
    #pragma unroll
    for (int bi = 0; bi < 2; bi++){
      const int b = 2*wv8 + bi;
      float a1 = fc1b_r;
      #pragma unroll
      for (int k4 = 0; k4 < 16; k4++){
        const float* wp = &fc1w_s[ln*68 + k4*4];
        const float* hp = &Hlast[b][k4*4];
        a1 += wp[0]*hp[0] + wp[1]*hp[1] + wp[2]*hp[2] + wp[3]*hp[3];
      }
      a1 += dval_s[b] * fc1w_s[ln*68 + 64];
      float v = a1 * fc2w_r;
      #pragma unroll
      for (int off = 32; off > 0; off >>= 1) v += __shfl_xor(v, off);
      o2[bi] = v + fc2b_r;
    }
    if (ln == 0){
      #pragma unroll
      for (int bi = 0; bi < 2; bi++){
        const int b = 2*wv8 + bi;
        out[(bg0 + b)*24 + s] = o2[bi];
        win_s[s % WIN][b] = o2[bi];
      }
    }
  };

  if (isA){
    // =================== A-branch: LSTM1 producer ===================
    bf16x8 A1hi[4][2], A1lo[4][2], Ain1[4];
    f32x4 b1c[4];
    #pragma unroll
    for (int e = 0; e < 4; e++){
      const int ja = 64*e + 16*wv + n;
      #pragma unroll
      for (int kt = 0; kt < 2; kt++){
        const float* pw = Whh1 + ja*64 + kt*32 + q*8;
        #pragma unroll
        for (int jj = 0; jj < 8; jj++){ short h,l; split_s(pw[jj], h, l); A1hi[e][kt][jj] = h; A1lo[e][kt][jj] = l; }
      }
      bf16x8 ain = {0,0,0,0,0,0,0,0};
      if (q == 0){ short wh, wl; split_s(Wih1[ja], wh, wl); ain[0] = wh; ain[1] = wh; ain[2] = wl; }
      Ain1[e] = ain;
      const int jc = 64*e + u0;
      #pragma unroll
      for (int r = 0; r < 4; r++) b1c[e][r] = bih1[jc+r] + bhh1[jc+r];
    }
    float c1[4];

    auto lstm1 = [&](int rb, int wb, int slot, int t, bool first){
      f32x4 acc[4];
      bf16x8 bin = {0,0,0,0,0,0,0,0};
      { float xv = win_s[slot][n]; uint32_t xh, xl; split_t(xv, xh, xl);
        if (q == 0){ bin[0] = (short)xh; bin[1] = (short)xl; bin[2] = (short)xh; } }
      if (first){
        #pragma unroll
        for (int e = 0; e < 4; e++) acc[e] = mfma16(Ain1[e], bin, b1c[e]);
      } else {
        bf16x8 Bh0 = *(const bf16x8*)&aS[FB(rb,0,0)+rdo];
        bf16x8 Bl0 = *(const bf16x8*)&aS[FB(rb,1,0)+rdo];
        bf16x8 Bh1 = *(const bf16x8*)&aS[FB(rb,0,1)+rdo];
        bf16x8 Bl1 = *(const bf16x8*)&aS[FB(rb,1,1)+rdo];
        #pragma unroll
        for (int e = 0; e < 4; e++){
          f32x4 a = b1c[e];
          a = mfma16(A1hi[e][0], Bh0, a);
          a = mfma16(A1hi[e][0], Bl0, a);
          a = mfma16(A1lo[e][0], Bh0, a);
          a = mfma16(A1hi[e][1], Bh1, a);
          a = mfma16(A1hi[e][1], Bl1, a);
          a = mfma16(A1lo[e][1], Bh1, a);
          a = mfma16(Ain1[e], bin, a);
          acc[e] = a;
        }
      }
      float hn[4];
      lstm_epi(acc, c1, hn);
      uint32_t ph[4], pl[4];
      #pragma unroll
      for (int r = 0; r < 4; r++) split_t(hn[r], ph[r], pl[r]);
      *(uint2*)&aS[FB(wb,0,kt_)+wro] = make_uint2(ph[0] | (ph[1]<<16), ph[2] | (ph[3]<<16));
      *(uint2*)&aS[FB(wb,1,kt_)+wro] = make_uint2(pl[0] | (pl[1]<<16), pl[2] | (pl[3]<<16));
      uint32_t sh[4], sl[4];
      #pragma unroll
      for (int r = 0; r < 4; r++){ bool pos = hn[r] > 0.0f; sh[r] = pos ? ph[r] : 0u; sl[r] = pos ? pl[r] : 0u; }
      short* Hp = hblk + (size_t)t * 2048;
      *(uint2*)&Hp[gwo]        = make_uint2(sh[0] | (sh[1]<<16), sh[2] | (sh[3]<<16));
      *(uint2*)&Hp[1024 + gwo] = make_uint2(sl[0] | (sl[1]<<16), sl[2] | (sl[3]<<16));
    };

    // ---- sweep 0: A(0) alone. 168 barriers.
    #pragma unroll
    for (int r = 0; r < 4; r++) c1[r] = 0.0f;
    for (int t = 0; t < WIN; t++){
      __syncthreads();
      lstm1(t & 1, (t & 1) ^ 1, t, t, t == 0);
    }
    #pragma unroll
    for (int r = 0; r < 4; r++) cS[u0 + r][n] = c1[r];   // c1-final handoff

    // ---- fused sweeps sg=1..23. 170 barriers each.
    for (int sg = 1; sg < NSTEPS; sg++){
      #pragma unroll
      for (int r = 0; r < 4; r++) c1[r] = 0.0f;
      int slot = sg;
      __syncthreads();                       // t=0
      lstm1(0, 1, slot, 0, true);
      slot++;
      for (int t = 1; t < WIN-1; t++){
        __syncthreads();
        lstm1(t & 1, (t & 1) ^ 1, slot, t, false);
        slot++; if (slot == WIN) slot = 0;
      }
      __syncthreads();                       // (a): B does lstm2(167)
      __syncthreads();                       // (b): Hlast ready
      fc_head(sg - 1);
      __syncthreads();                       // (c): window updated
      lstm1(1, 0, slot, WIN-1, false);       // slot == sg-1, final h1 -> aS[0]
      #pragma unroll
      for (int r = 0; r < 4; r++) cS[u0 + r][n] = c1[r];
    }

    // ---- final sweep: B(23) alone. 169 barriers then FC.
    for (int i = 0; i < WIN + 1; i++) __syncthreads();
    fc_head(NSTEPS - 1);

  } else {
    // =================== B-branch: LSTM2 consumer ===================
    bf16x8 A2hi[4][4], A2lo[4][4];
    f32x4 b2c[4];
    #pragma unroll
    for (int e = 0; e < 4; e++){
      const int ja = 64*e + 16*wv + n;
      #pragma unroll
      for (int kt = 0; kt < 4; kt++){
        const float* pw = (kt < 2 ? (Wih2 + ja*64 + kt*32) : (Whh2 + ja*64 + (kt-2)*32)) + q*8;
        #pragma unroll
        for (int jj = 0; jj < 8; jj++){ short h,l; split_s(pw[jj], h, l); A2hi[e][kt][jj] = h; A2lo[e][kt][jj] = l; }
      }
      const int jc = 64*e + u0;
      #pragma unroll
      for (int r = 0; r < 4; r++) b2c[e][r] = bih2[jc+r] + bhh2[jc+r];
    }
    float c2[4];
    bf16x8 ch0, cl0, ch1, cl1, nh0, nl0, nh1, nl1;

    auto loadc = [&](int t){
      const short* Hp = hblk + (size_t)t * 2048;
      ch0 = *(const bf16x8*)&Hp[ro];
      cl0 = *(const bf16x8*)&Hp[1024 + ro];
      ch1 = *(const bf16x8*)&Hp[512 + ro];
      cl1 = *(const bf16x8*)&Hp[1536 + ro];
    };
    auto loadn = [&](int t){
      const short* Hp = hblk + (size_t)t * 2048;
      nh0 = *(const bf16x8*)&Hp[ro];
      nl0 = *(const bf16x8*)&Hp[1024 + ro];
      nh1 = *(const bf16x8*)&Hp[512 + ro];
      nl1 = *(const bf16x8*)&Hp[1536 + ro];
    };
    auto shift = [&](){ ch0 = nh0; cl0 = nl0; ch1 = nh1; cl1 = nl1; };

    auto lstm2 = [&](const short* Sr, int rb, short* Sw, int wb, bool last){
      bf16x8 L2h0 = *(const bf16x8*)&Sr[FB(rb,0,0)+rdo];
      bf16x8 L2l0 = *(const bf16x8*)&Sr[FB(rb,1,0)+rdo];
      bf16x8 L2h1 = *(const bf16x8*)&Sr[FB(rb,0,1)+rdo];
      bf16x8 L2l1 = *(const bf16x8*)&Sr[FB(rb,1,1)+rdo];
      f32x4 acc[4];
      #pragma unroll
      for (int e = 0; e < 4; e++){
        f32x4 a = b2c[e];
        a = mfma16(A2hi[e][0], ch0, a);
        a = mfma16(A2hi[e][0], cl0, a);
        a = mfma16(A2lo[e][0], ch0, a);
        a = mfma16(A2hi[e][1], ch1, a);
        a = mfma16(A2hi[e][1], cl1, a);
        a = mfma16(A2lo[e][1], ch1, a);
        a = mfma16(A2hi[e][2], L2h0, a);
        a = mfma16(A2hi[e][2], L2l0, a);
        a = mfma16(A2lo[e][2], L2h0, a);
        a = mfma16(A2hi[e][3], L2h1, a);
        a = mfma16(A2hi[e][3], L2l1, a);
        a = mfma16(A2lo[e][3], L2h1, a);
        acc[e] = a;
      }
      float hn[4];
      lstm_epi(acc, c2, hn);
      if (!last){
        uint32_t ph[4], pl[4];
        #pragma unroll
        for (int r = 0; r < 4; r++) split_t(hn[r], ph[r], pl[r]);
        *(uint2*)&Sw[FB(wb,0,kt_)+wro] = make_uint2(ph[0] | (ph[1]<<16), ph[2] | (ph[3]<<16));
        *(uint2*)&Sw[FB(wb,1,kt_)+wro] = make_uint2(pl[0] | (pl[1]<<16), pl[2] | (pl[3]<<16));
      } else {
        #pragma unroll
        for (int r = 0; r < 4; r++) Hlast[n][u0 + r] = fmaxf(hn[r], 0.0f);
      }
    };

    // ---- sweep 0: idle. 168 barriers.
    for (int i = 0; i < WIN; i++) __syncthreads();

    // ---- fused sweeps sg=1..23: B(sg-1). 170 barriers each.
    for (int sg = 1; sg < NSTEPS; sg++){
      loadc(0);                              // sweep seed: must drain at the
      loadn(1);                              // t=0 barrier (A rewrites slot 0
      __syncthreads();                       // in interval 0). Once per sweep.
      #pragma unroll
      for (int r = 0; r < 4; r++) c2[r] = cS[u0 + r][n];
      lstm2(aS, 0, bS, 1, false);            // t=0: h2-init from aS[0]
      shift();
      for (int t = 1; t < WIN-1; t++){
        __syncthreads();
        loadn(t + 1);                        // R9: hoisted AFTER barrier -- a
                                             // full interval to complete, no
                                             // vmcnt(0) drain stall.
        lstm2(bS, t & 1, bS, (t & 1) ^ 1, false);
        shift();
      }
      __syncthreads();                       // (a)
      lstm2(bS, 1, bS, 0, true);             // t=167 -> Hlast
      __syncthreads();                       // (b)
      fc_head(sg - 1);
      __syncthreads();                       // (c)
    }

    // ---- final sweep: B(23). 169 barriers then FC.
    {
      loadc(0);
      loadn(1);
      __syncthreads();
      #pragma unroll
      for (int r = 0; r < 4; r++) c2[r] = cS[u0 + r][n];
      lstm2(aS, 0, bS, 1, false);
      shift();
      for (int t = 1; t < WIN-1; t++){
        __syncthreads();
        loadn(t + 1);                        // R9 hoist (no writer conflicts
                                             // at all in the final sweep)
        lstm2(bS, t & 1, bS, (t & 1) ^ 1, false);
        shift();
      }
      __syncthreads();
      lstm2(bS, 1, bS, 0, true);             // t=167
      __syncthreads();
      fc_head(NSTEPS - 1);
    }
  }
}

// ============================================================================
// Fallback (no workspace): replay scheme, 256 threads. Safety only.
// ============================================================================
__global__ __launch_bounds__(256, 1) void lstm_fallback_kernel(
  const float* __restrict__ x,    const float* __restrict__ Wih1, const float* __restrict__ Whh1,
  const float* __restrict__ bih1, const float* __restrict__ bhh1,
  const float* __restrict__ Wih2, const float* __restrict__ Whh2,
  const float* __restrict__ bih2, const float* __restrict__ bhh2,
  const float* __restrict__ fc1w, const float* __restrict__ fc1b,
  const float* __restrict__ fc2w, const float* __restrict__ fc2b,
  float* __restrict__ out)
{
  __shared__ __align__(16) short aS[2*2*2*FBLK];
  __shared__ __align__(16) short r1f[2*2*2*FBLK];
  __shared__ __align__(16) short rlf[2*2*2*FBLK];
  __shared__ float win_s[WIN][NB];
  __shared__ float Hlast[NB][68];
  __shared__ float fc1w_s[64*68];
  __shared__ float dval_s[NB];

  const int tid = threadIdx.x;
  const int wv  = tid >> 6;
  const int ln  = tid & 63;
  const int q   = ln >> 4;
  const int n   = ln & 15;
  const int bg0 = blockIdx.x * NB;
  const int u0  = 16*wv + 4*q;
  const int kt_  = u0 >> 5;
  const int q2_  = (u0 >> 3) & 3;
  const int jj0_ = u0 & 7;
  const int rdo  = q*FROW + n*8;
  const int wro  = q2_*FROW + n*8 + jj0_;

  for (int i = tid; i < WIN*NB; i += 256){ int t = i >> 4, b = i & 15; win_s[t][b] = x[(bg0 + b)*169 + t]; }
  for (int i = tid; i < 64*65; i += 256){ int j = i / 65, k = i % 65; fc1w_s[j*68 + k] = fc1w[i]; }
  if (tid < NB) dval_s[tid] = x[(bg0 + tid)*169 + 168];

  const float fc1b_r = fc1b[ln];
  const float fc2w_r = fc2w[ln];
  const float fc2b_r = fc2b[0];

  bf16x8 A1hi[4][2], A1lo[4][2], Ain1[4];
  bf16x8 A2hi[4][4], A2lo[4][4];
  f32x4 b1c[4], b2c[4];
  #pragma unroll
  for (int e = 0; e < 4; e++){
    const int ja = 64*e + 16*wv + n;
    #pragma unroll
    for (int kt = 0; kt < 2; kt++){
      const float* pw = Whh1 + ja*64 + kt*32 + q*8;
      #pragma unroll
      for (int jj = 0; jj < 8; jj++){ short h,l; split_s(pw[jj], h, l); A1hi[e][kt][jj] = h; A1lo[e][kt][jj] = l; }
    }
    #pragma unroll
    for (int kt = 0; kt < 4; kt++){
      const float* pw = (kt < 2 ? (Wih2 + ja*64 + kt*32) : (Whh2 + ja*64 + (kt-2)*32)) + q*8;
      #pragma unroll
      for (int jj = 0; jj < 8; jj++){ short h,l; split_s(pw[jj], h, l); A2hi[e][kt][jj] = h; A2lo[e][kt][jj] = l; }
    }
    bf16x8 ain = {0,0,0,0,0,0,0,0};
    if (q == 0){ short wh, wl; split_s(Wih1[ja], wh, wl); ain[0] = wh; ain[1] = wh; ain[2] = wl; }
    Ain1[e] = ain;
    const int jc = 64*e + u0;
    #pragma unroll
    for (int r = 0; r < 4; r++){
      b1c[e][r] = bih1[jc+r] + bhh1[jc+r];
      b2c[e][r] = bih2[jc+r] + bhh2[jc+r];
    }
  }

  float c1[4], c2[4], c1r[4];

  auto lstm1_step = [&](short* S, float* cst, int rb, int wb, int slot, bool relu_out){
    bf16x8 Bh0 = *(const bf16x8*)&S[FB(rb,0,0)+rdo];
    bf16x8 Bl0 = *(const bf16x8*)&S[FB(rb,1,0)+rdo];
    bf16x8 Bh1 = *(const bf16x8*)&S[FB(rb,0,1)+rdo];
    bf16x8 Bl1 = *(const bf16x8*)&S[FB(rb,1,1)+rdo];
    bf16x8 bin = {0,0,0,0,0,0,0,0};
    { float xv = win_s[slot][n]; uint32_t xh, xl; split_t(xv, xh, xl);
      if (q == 0){ bin[0] = (short)xh; bin[1] = (short)xl; bin[2] = (short)xh; } }
    f32x4 acc[4];
    #pragma unroll
    for (int e = 0; e < 4; e++){
      f32x4 a = b1c[e];
      a = mfma16(A1hi[e][0], Bh0, a);
      a = mfma16(A1hi[e][0], Bl0, a);
      a = mfma16(A1lo[e][0], Bh0, a);
      a = mfma16(A1hi[e][1], Bh1, a);
      a = mfma16(A1hi[e][1], Bl1, a);
      a = mfma16(A1lo[e][1], Bh1, a);
      a = mfma16(Ain1[e], bin, a);
      acc[e] = a;
    }
    float hn[4];
    lstm_epi(acc, cst, hn);
    uint32_t ph[4], pl[4];
    #pragma unroll
    for (int r = 0; r < 4; r++) split_t(hn[r], ph[r], pl[r]);
    *(uint2*)&S[FB(wb,0,kt_)+wro] = make_uint2(ph[0] | (ph[1]<<16), ph[2] | (ph[3]<<16));
    *(uint2*)&S[FB(wb,1,kt_)+wro] = make_uint2(pl[0] | (pl[1]<<16), pl[2] | (pl[3]<<16));
    if (relu_out){
      uint32_t sh[4], sl[4];
      #pragma unroll
      for (int r = 0; r < 4; r++){ bool pos = hn[r] > 0.0f; sh[r] = pos ? ph[r] : 0u; sl[r] = pos ? pl[r] : 0u; }
      *(uint2*)&rlf[FB(rb,0,kt_)+wro] = make_uint2(sh[0] | (sh[1]<<16), sh[2] | (sh[3]<<16));
      *(uint2*)&rlf[FB(rb,1,kt_)+wro] = make_uint2(sl[0] | (sl[1]<<16), sl[2] | (sl[3]<<16));
    }
  };

  auto lstm2_core = [&](bf16x8 L1h0, bf16x8 L1l0, bf16x8 L1h1, bf16x8 L1l1,
                        int rbuf, int wbuf, bool last){
    bf16x8 L2h0 = *(const bf16x8*)&aS[FB(rbuf,0,0)+rdo];
    bf16x8 L2l0 = *(const bf16x8*)&aS[FB(rbuf,1,0)+rdo];
    bf16x8 L2h1 = *(const bf16x8*)&aS[FB(rbuf,0,1)+rdo];
    bf16x8 L2l1 = *(const bf16x8*)&aS[FB(rbuf,1,1)+rdo];
    f32x4 acc[4];
    #pragma unroll
    for (int e = 0; e < 4; e++){
      f32x4 a = b2c[e];
      a = mfma16(A2hi[e][0], L1h0, a);
      a = mfma16(A2hi[e][0], L1l0, a);
      a = mfma16(A2lo[e][0], L1h0, a);
      a = mfma16(A2hi[e][1], L1h1, a);
      a = mfma16(A2hi[e][1], L1l1, a);
      a = mfma16(A2lo[e][1], L1h1, a);
      a = mfma16(A2hi[e][2], L2h0, a);
      a = mfma16(A2hi[e][2], L2l0, a);
      a = mfma16(A2lo[e][2], L2h0, a);
      a = mfma16(A2hi[e][3], L2h1, a);
      a = mfma16(A2hi[e][3], L2l1, a);
      a = mfma16(A2lo[e][3], L2h1, a);
      acc[e] = a;
    }
    float hn[4];
    lstm_epi(acc, c2, hn);
    if (!last){
      uint32_t ph[4], pl[4];
      #pragma unroll
      for (int r = 0; r < 4; r++) split_t(hn[r], ph[r], pl[r]);
      *(uint2*)&aS[FB(wbuf,0,kt_)+wro] = make_uint2(ph[0] | (ph[1]<<16), ph[2] | (ph[3]<<16));
      *(uint2*)&aS[FB(wbuf,1,kt_)+wro] = make_uint2(pl[0] | (pl[1]<<16), pl[2] | (pl[3]<<16));
    } else {
      #pragma unroll
      for (int r = 0; r < 4; r++) Hlast[n][u0 + r] = fmaxf(hn[r], 0.0f);
    }
  };

  for (int s = 0; s < NSTEPS; s++){
    { int* p = (int*)&aS[0];
      for (int i = tid; i < BUF_INTS; i += 256) p[i] = 0; }
    #pragma unroll
    for (int r = 0; r < 4; r++) c1[r] = 0.0f;
    int slot = s;
    for (int t = 0; t < WIN; t++){
      __syncthreads();
      lstm1_step(aS, c1, t & 1, (t & 1) ^ 1, slot, false);
      slot++; if (slot == WIN) slot = 0;
    }
    #pragma unroll
    for (int r = 0; r < 4; r++){ c2[r] = c1[r]; c1r[r] = 0.0f; }
    { int* p = (int*)&r1f[0];
      for (int i = tid; i < BUF_INTS; i += 256) p[i] = 0; }
    slot = s;
    __syncthreads();
    lstm1_step(r1f, c1r, 0, 1, slot, true);
    slot++;
    for (int i = 1; i < WIN; i++){
      __syncthreads();
      const int rb = i & 1, wb = rb ^ 1;
      lstm1_step(r1f, c1r, rb, wb, slot, true);
      bf16x8 L1h0 = *(const bf16x8*)&rlf[FB(wb,0,0)+rdo];
      bf16x8 L1l0 = *(const bf16x8*)&rlf[FB(wb,1,0)+rdo];
      bf16x8 L1h1 = *(const bf16x8*)&rlf[FB(wb,0,1)+rdo];
      bf16x8 L1l1 = *(const bf16x8*)&rlf[FB(wb,1,1)+rdo];
      lstm2_core(L1h0, L1l0, L1h1, L1l1, wb, rb, false);
      slot++; if (slot == WIN) slot = 0;
    }
    __syncthreads();
    {
      const int rb = (WIN - 1) & 1;
      bf16x8 L1h0 = *(const bf16x8*)&rlf[FB(rb,0,0)+rdo];
      bf16x8 L1l0 = *(const bf16x8*)&rlf[FB(rb,1,0)+rdo];
      bf16x8 L1h1 = *(const bf16x8*)&rlf[FB(rb,0,1)+rdo];
      bf16x8 L1l1 = *(const bf16x8*)&rlf[FB(rb,1,1)+rdo];
      lstm2_core(L1h0, L1l0, L1h1, L1l1, rb, 0, true);
    }
    __syncthreads();
    {
      float o4[4];
      #pragma unroll
      for (int bi = 0; bi < 4; bi++){
        const int b = 4*wv + bi;
        float a1 = fc1b_r;
        #pragma unroll
        for (int k4 = 0; k4 < 16; k4++){
          const float* wp = &fc1w_s[ln*68 + k4*4];
          const float* hp = &Hlast[b][k4*4];
          a1 += wp[0]*hp[0] + wp[1]*hp[1] + wp[2]*hp[2] + wp[3]*hp[3];
        }
        a1 += dval_s[b] * fc1w_s[ln*68 + 64];
        float v = a1 * fc2w_r;
        #pragma unroll
        for (int off = 32; off > 0; off >>= 1) v += __shfl_xor(v, off);
        o4[bi] = v + fc2b_r;
      }
      if (ln == 0){
        #pragma unroll
        for (int bi = 0; bi < 4; bi++){
          const int b = 4*wv + bi;
          out[(bg0 + b)*24 + s] = o4[bi];
          win_s[s % WIN][b] = o4[bi];
        }
      }
    }
  }
}

extern "C" void kernel_launch(void* const* d_in, const int* in_sizes, int n_in,
                              void* d_out, int out_size, void* d_ws, size_t ws_size,
                              hipStream_t stream) {
  (void)in_sizes; (void)n_in; (void)out_size;
  const size_t need = (size_t)NBLK * WIN * 2048 * sizeof(short);   // ~176 MB
  if (ws_size >= need){
    lstm_fused_kernel<<<dim3(NBLK), dim3(NT), 0, stream>>>(
        (const float*)d_in[0], (const float*)d_in[1], (const float*)d_in[2],
        (const float*)d_in[3], (const float*)d_in[4], (const float*)d_in[5],
        (const float*)d_in[6], (const float*)d_in[7], (const float*)d_in[8],
        (const float*)d_in[9], (const float*)d_in[10], (const float*)d_in[11],
        (const float*)d_in[12], (float*)d_out, (short*)d_ws);
  } else {
    lstm_fallback_kernel<<<dim3(NBLK), dim3(256), 0, stream>>>(
        (const float*)d_in[0], (const float*)d_in[1], (const float*)d_in[2],
        (const float*)d_in[3], (const float*)d_in[4], (const float*)d_in[5],
        (const float*)d_in[6], (const float*)d_in[7], (const float*)d_in[8],
        (const float*)d_in[9], (const float*)d_in[10], (const float*)d_in[11],
        (const float*)d_in[12], (float*)d_out);
  }
}